// Round 6
// baseline (210.918 us; speedup 1.0000x reference)
//
#include <hip/hip_runtime.h>
#include <cstdint>

typedef unsigned short u16;
typedef __bf16 bf16;
typedef bf16 bf16x8 __attribute__((ext_vector_type(8)));
typedef u16 u16x4 __attribute__((ext_vector_type(4)));
typedef u16 u16x8 __attribute__((ext_vector_type(8)));
typedef float f32x4 __attribute__((ext_vector_type(4)));

__device__ __forceinline__ u16 f2b(float f) {
    return __builtin_bit_cast(u16, (bf16)f);
}
__device__ __forceinline__ float b2f(u16 u) {
    return __uint_as_float(((unsigned)u) << 16);
}
__device__ __forceinline__ void load_lds16(const void* g, void* l) {
    auto gp = reinterpret_cast<const __attribute__((address_space(1))) void*>(
        reinterpret_cast<uintptr_t>(g));
    auto lp = reinterpret_cast<__attribute__((address_space(3))) void*>(
        reinterpret_cast<uintptr_t>(l));
    __builtin_amdgcn_global_load_lds(gp, lp, 16, 0, 0);
}
__device__ __forceinline__ f32x4 mfma16(bf16x8 a, bf16x8 b, f32x4 c) {
    return __builtin_amdgcn_mfma_f32_16x16x32_bf16(a, b, c, 0, 0, 0);
}

// ---------------------------------------------------------------- convert x -> bf16
__global__ __launch_bounds__(256) void convx_kernel(const float* __restrict__ x,
                                                    u16* __restrict__ xb, int n4) {
    int i = blockIdx.x * blockDim.x + threadIdx.x;
    int stride = gridDim.x * blockDim.x;
    for (; i < n4; i += stride) {
        float4 v = ((const float4*)x)[i];
        u16x4 r;
        r[0] = f2b(v.x); r[1] = f2b(v.y); r[2] = f2b(v.z); r[3] = f2b(v.w);
        *(u16x4*)&xb[(size_t)i * 4] = r;
    }
}

// ------------------- combined transpose+convert for both weights: [K=768][N] f32 -> [N][768] bf16
__global__ __launch_bounds__(256) void wtrans2_kernel(const float* __restrict__ wa,
                                                      const float* __restrict__ wp,
                                                      u16* __restrict__ wTa,
                                                      u16* __restrict__ wTp) {
    __shared__ float tile[32][33];
    const int bx = blockIdx.x;
    const float* w;
    u16* wT;
    int N, n0;
    if (bx < 72) { w = wa; wT = wTa; N = 2304; n0 = bx * 32; }
    else         { w = wp; wT = wTp; N = 768;  n0 = (bx - 72) * 32; }
    const int K = 768;
    int tx = threadIdx.x, ty = threadIdx.y;  // (32, 8)
    int k0 = blockIdx.y * 32;
#pragma unroll
    for (int i = 0; i < 4; ++i)
        tile[ty + i * 8][tx] = w[(size_t)(k0 + ty + i * 8) * N + n0 + tx];
    __syncthreads();
#pragma unroll
    for (int i = 0; i < 4; ++i)
        wT[(size_t)(n0 + ty + i * 8) * K + k0 + tx] = f2b(tile[tx][ty + i * 8]);
}

// ---------------------------------------------------------------- GEMM: C[M][N] = A[M][K] * Bt[N][K]^T + bias
// 128x128 tile, 4 waves, 16x16x32 MFMA. Double-buffered gload_lds staging (stage
// next tile AFTER the single per-iter barrier -> depth-1 pipeline, latency hidden
// under compute). MFMA operands SWAPPED (mfma(b,a)) so lane holds 4 consecutive
// C-columns -> coalesced vectorized epilogue. XCD-aware block swizzle (T1).
template <bool OUT_BF16>
__global__ __launch_bounds__(256, 2) void gemm_kernel(const u16* __restrict__ A,
                                                      const u16* __restrict__ Bt,
                                                      const float* __restrict__ bias,
                                                      void* __restrict__ out,
                                                      int M, int N, int K) {
    __shared__ __align__(16) u16 SMEM[4 * 128 * 64];   // A0,B0,A1,B1 (64 KB)
    const int tid = threadIdx.x;
    const int wave = tid >> 6, lane = tid & 63;
    const int l15 = lane & 15, lg = lane >> 4;
    // XCD-aware swizzle (T1); nwg % 8 == 0 for both GEMMs here.
    const int gx = gridDim.x;
    const int nwg = gx * gridDim.y;
    const int lin = blockIdx.y * gx + blockIdx.x;
    const int swz = (lin & 7) * (nwg >> 3) + (lin >> 3);
    const int tm = (swz / gx) * 128, tn = (swz % gx) * 128;
    const int wr = (wave >> 1) * 64, wc = (wave & 1) * 64;

    f32x4 acc[4][4] = {};

    const int rbase = wave * 8 + (lane >> 3);
    const int sslot = (lane & 7) ^ (rbase & 7);
    const u16* gA = A + (size_t)(tm + rbase) * K + sslot * 8;
    const u16* gB = Bt + (size_t)(tn + rbase) * K + sslot * 8;
    const int woff = wave * 8 * 64;
    const int nkt = K >> 6;

    // prologue: stage tile 0 into buffer 0
#pragma unroll
    for (int i = 0; i < 4; ++i) {
        load_lds16(gA + (size_t)i * 32 * K, SMEM + woff + i * 32 * 64);
        load_lds16(gB + (size_t)i * 32 * K, SMEM + 8192 + woff + i * 32 * 64);
    }

    for (int kt = 0; kt < nkt; ++kt) {
        __syncthreads();  // drains buf[cur] loads (issued one iter ago) + prev reads done
        const int cur = kt & 1;
        if (kt + 1 < nkt) {
            u16* ldsA = SMEM + (cur ^ 1) * 2 * 8192 + woff;
            u16* ldsB = ldsA + 8192;
#pragma unroll
            for (int i = 0; i < 4; ++i) {
                load_lds16(gA + (size_t)i * 32 * K + (kt + 1) * 64, ldsA + i * 32 * 64);
                load_lds16(gB + (size_t)i * 32 * K + (kt + 1) * 64, ldsB + i * 32 * 64);
            }
        }
        const u16* As = SMEM + cur * 2 * 8192;
        const u16* Bs = As + 8192;
#pragma unroll
        for (int kk = 0; kk < 64; kk += 32) {
            const int sb = kk >> 3;
            bf16x8 af[4], bfr[4];
#pragma unroll
            for (int m = 0; m < 4; ++m) {
                int row = wr + m * 16 + l15;
                af[m] = *(const bf16x8*)&As[row * 64 + (((sb + lg) ^ (row & 7))) * 8];
            }
#pragma unroll
            for (int n = 0; n < 4; ++n) {
                int row = wc + n * 16 + l15;
                bfr[n] = *(const bf16x8*)&Bs[row * 64 + (((sb + lg) ^ (row & 7))) * 8];
            }
#pragma unroll
            for (int m = 0; m < 4; ++m)
#pragma unroll
                for (int n = 0; n < 4; ++n)
                    acc[m][n] = mfma16(bfr[n], af[m], acc[m][n]);  // swapped: cols on regs
        }
    }

    // epilogue: lane holds C[row = tm+wr+m*16+l15][col = tn+wc+n*16+lg*4 + r]
#pragma unroll
    for (int m = 0; m < 4; ++m) {
        const size_t row = (size_t)(tm + wr + m * 16 + l15);
#pragma unroll
        for (int n = 0; n < 4; ++n) {
            const int col = tn + wc + n * 16 + lg * 4;
            f32x4 v = acc[m][n] + *(const f32x4*)&bias[col];
            if constexpr (OUT_BF16) {
                u16x4 pk;
#pragma unroll
                for (int r = 0; r < 4; ++r) pk[r] = f2b(v[r]);
                *(u16x4*)&((u16*)out)[row * N + col] = pk;
            } else {
                *(f32x4*)&((float*)out)[row * N + col] = v;
            }
        }
    }
}

// ---------------------------------------------------------------- V transpose + fused per-64-tile colsum
// qkv V-part -> vt[bh][d=64][s=2048]; ts_raw[bh][st][d] = sum_s V[st*64+s][d]
__global__ __launch_bounds__(256) void vtrans_kernel(const u16* __restrict__ qkv,
                                                     u16* __restrict__ vt,
                                                     float* __restrict__ ts_raw) {
    __shared__ __align__(16) u16 tile[64][72];
    __shared__ float red2[64][4];
    const int st = blockIdx.x, bh = blockIdx.y;
    const int b = bh / 12, h = bh % 12;
    const int t = threadIdx.x;
    const int sr = t >> 2, c4 = (t & 3) * 16;
    const u16* src = qkv + (size_t)(b * 2048 + st * 64 + sr) * 2304 + 1536 + h * 64 + c4;
    *(u16x8*)&tile[sr][c4] = *(const u16x8*)src;
    *(u16x8*)&tile[sr][c4 + 8] = *(const u16x8*)(src + 8);
    __syncthreads();
    const int dr = t >> 2, s4 = (t & 3) * 16;
    u16x8 w0, w1;
    float psum = 0.f;
#pragma unroll
    for (int j = 0; j < 8; ++j) {
        w0[j] = tile[s4 + j][dr];
        w1[j] = tile[s4 + 8 + j][dr];
        psum += b2f(w0[j]) + b2f(w1[j]);
    }
    u16* dst = vt + ((size_t)bh * 64 + dr) * 2048 + st * 64 + s4;
    *(u16x8*)dst = w0;
    *(u16x8*)(dst + 8) = w1;
    red2[dr][t & 3] = psum;
    __syncthreads();
    if (t < 64)
        ts_raw[((size_t)bh * 32 + st) * 64 + t] =
            red2[t][0] + red2[t][1] + red2[t][2] + red2[t][3];
}

// ---------------------------------------------------------------- attention
// Swapped-operand flash, QBLK=64, KBLK=64, defer-max, K-row permutation so the
// softmax'd P is ALREADY in PV's B-fragment register layout (no P LDS round-trip).
// sigma(rho) = ((rho&0x1C)<<1) | ((rho>>5)<<2) | (rho&3): LDS row rho holds K row sigma(rho);
// then lane's QK output p[n][r] = P[k=(n&1)*32+lg*8+(n>>1)*4+r][q=l15] and PV's
// B-operand for k-slice ks is bp_ks[j] = p[2*(j>>2)+ks][j&3] -- register relabel only.
__global__ __launch_bounds__(256, 5) void attn_kernel(const u16* __restrict__ qkv,
                                                      const u16* __restrict__ vt,
                                                      const float* __restrict__ ts_raw,
                                                      u16* __restrict__ aout) {
    __shared__ __align__(16) u16 Ks[2][64 * 64];
    __shared__ __align__(16) u16 Vs[2][64 * 64];   // transposed V: [d][k], true-k columns
    const int bh = blockIdx.x;                     // bh fastest: same-bh blocks share XCD L2
    const int qt = 31 - blockIdx.y;                // longest-first dispatch
    const int b = bh / 12, h = bh % 12;
    const int tid = threadIdx.x, wave = tid >> 6, lane = tid & 63;
    const int l15 = lane & 15, lg = lane >> 4;
    const int q0 = qt * 64 + wave * 16;
    const size_t rowbase = (size_t)b * 2048;

    // Q fragment (B-operand): lane holds Q[q0+l15][ks*32 + lg*8 .. +8]
    bf16x8 qf[2];
#pragma unroll
    for (int ks = 0; ks < 2; ++ks)
        qf[ks] = *(const bf16x8*)(qkv + (rowbase + q0 + l15) * 2304 + h * 64 +
                                  ks * 32 + lg * 8);

    f32x4 o[4] = {};          // O^T: lane holds O[q=q0+l15][d = dn*16 + lg*4 + r]
    float mrun = -1e30f;
    float lrun = 0.f;         // per-lane partial; folded across lane-groups after loop

    // staging constants (gload_lds: linear LDS dest, pre-swizzled global source)
    const int rbase = wave * 8 + (lane >> 3);
    const int sslot = (lane & 7) ^ (rbase & 7);
    const int sig0 = ((rbase & 0x1C) << 1) | (rbase & 3);   // K-row permutation base
    const u16* gK = qkv + (rowbase + sig0) * 2304 + 768 + h * 64 + sslot * 8;
    const u16* gV = vt + ((size_t)bh * 64 + rbase) * 2048 + sslot * 8;
    const int ldsoff = wave * 8 * 64;

    const int nkt = qt + 1;
    // prologue: stage kt=0 into buffer 0 (K rows permuted: inst i covers sig0 + i*4)
#pragma unroll
    for (int i = 0; i < 2; ++i) {
        load_lds16(gK + (size_t)(i * 4) * 2304, &Ks[0][ldsoff + i * 32 * 64]);
        load_lds16(gV + (size_t)(i * 32) * 2048, &Vs[0][ldsoff + i * 32 * 64]);
    }

    for (int kt = 0; kt < nkt; ++kt) {
        __syncthreads();  // drains vmcnt: tile[cur] ready; prev-iter LDS reads done
        const int cur = kt & 1;
        if (kt + 1 < nkt) {
            const int nx = cur ^ 1;
#pragma unroll
            for (int i = 0; i < 2; ++i) {
                load_lds16(gK + (size_t)((kt + 1) * 64 + i * 4) * 2304,
                           &Ks[nx][ldsoff + i * 32 * 64]);
                load_lds16(gV + (size_t)(i * 32) * 2048 + (kt + 1) * 64,
                           &Vs[nx][ldsoff + i * 32 * 64]);
            }
        }

        // S^T = K Q^T (K rows permuted by sigma)
        f32x4 sacc[4] = {};
        __builtin_amdgcn_s_setprio(1);
#pragma unroll
        for (int ks = 0; ks < 2; ++ks) {
#pragma unroll
            for (int n = 0; n < 4; ++n) {
                int row = n * 16 + l15;
                bf16x8 ak = *(const bf16x8*)&Ks[cur][row * 64 +
                                                     (((ks * 4 + lg) ^ (row & 7))) * 8];
                sacc[n] = mfma16(ak, qf[ks], sacc[n]);
            }
        }
        __builtin_amdgcn_s_setprio(0);

        // reference mask trick on the diagonal tile (true k via sigma)
        if (kt == qt) {
            const int q = q0 + l15;
            const int kb = kt * 64 + lg * 8;
#pragma unroll
            for (int n = 0; n < 4; ++n) {
                const int kn = kb + (n & 1) * 32 + ((n >> 1) << 2);
#pragma unroll
                for (int r = 0; r < 4; ++r)
                    if (kn + r > q) sacc[n][r] = 1e-9f;
            }
        }

        // defer-max: lane-local max; rescale only when it grows >THR
        float mx = fmaxf(fmaxf(sacc[0][0], sacc[0][1]), fmaxf(sacc[0][2], sacc[0][3]));
#pragma unroll
        for (int n = 1; n < 4; ++n)
            mx = fmaxf(mx, fmaxf(fmaxf(sacc[n][0], sacc[n][1]),
                                 fmaxf(sacc[n][2], sacc[n][3])));
        if (__any(mx > mrun + 8.0f)) {
            float rm = fmaxf(mx, __shfl_xor(mx, 16));
            rm = fmaxf(rm, __shfl_xor(rm, 32));
            const float mnew = fmaxf(mrun, rm);
            const float alpha = __expf(mrun - mnew);
            mrun = mnew;
            lrun *= alpha;
#pragma unroll
            for (int dn = 0; dn < 4; ++dn) o[dn] *= alpha;
        }

        // exp (bounded by e^8) and pack straight into PV B-fragments (lane-local!)
#pragma unroll
        for (int n = 0; n < 4; ++n)
#pragma unroll
            for (int r = 0; r < 4; ++r) {
                float p = __expf(sacc[n][r] - mrun);
                lrun += p;
                sacc[n][r] = p;
            }
        bf16x8 bp0, bp1;
#pragma unroll
        for (int j = 0; j < 4; ++j) {
            bp0[j]     = (bf16)sacc[0][j];
            bp0[j + 4] = (bf16)sacc[2][j];
            bp1[j]     = (bf16)sacc[1][j];
            bp1[j + 4] = (bf16)sacc[3][j];
        }

        // O^T += V^T P^T
        __builtin_amdgcn_s_setprio(1);
#pragma unroll
        for (int ks = 0; ks < 2; ++ks) {
            bf16x8 bp = ks ? bp1 : bp0;
#pragma unroll
            for (int dn = 0; dn < 4; ++dn) {
                int row = dn * 16 + l15;
                bf16x8 av = *(const bf16x8*)&Vs[cur][row * 64 +
                                                     (((ks * 4 + lg) ^ (row & 7))) * 8];
                o[dn] = mfma16(av, bp, o[dn]);
            }
        }
        __builtin_amdgcn_s_setprio(0);
    }

    // fold per-lane l across the 4 lane-groups of this row (once, not per tile)
    lrun += __shfl_xor(lrun, 16);
    lrun += __shfl_xor(lrun, 32);

    // analytic future tail: all k >= (qt+1)*64 carry score exactly 1e-9
    if (qt < 31) {
        const float nf = (float)((31 - qt) * 64);
        const float mnew = fmaxf(mrun, 1e-9f);
        const float a = __expf(mrun - mnew);
        const float c = __expf(1e-9f - mnew);
        lrun = lrun * a + nf * c;
        f32x4 suf[4] = {};
        for (int t = qt + 1; t < 32; ++t) {
            const float* sp = ts_raw + ((size_t)bh * 32 + t) * 64;
#pragma unroll
            for (int dn = 0; dn < 4; ++dn)
                suf[dn] += *(const f32x4*)&sp[dn * 16 + lg * 4];
        }
#pragma unroll
        for (int dn = 0; dn < 4; ++dn)
            o[dn] = o[dn] * a + suf[dn] * c;
    }

    // normalize + store merged-head layout [B*S][768] bf16
    const float inv = 1.f / lrun;
    const size_t row = rowbase + q0 + l15;
#pragma unroll
    for (int dn = 0; dn < 4; ++dn) {
        u16x4 st;
#pragma unroll
        for (int r = 0; r < 4; ++r) st[r] = f2b(o[dn][r] * inv);
        *(u16x4*)&aout[row * 768 + h * 64 + dn * 16 + lg * 4] = st;
    }
}

// ---------------------------------------------------------------- launch
extern "C" void kernel_launch(void* const* d_in, const int* in_sizes, int n_in,
                              void* d_out, int out_size, void* d_ws, size_t ws_size,
                              hipStream_t stream) {
    const float* x      = (const float*)d_in[0];
    const float* w_attn = (const float*)d_in[1];
    const float* b_attn = (const float*)d_in[2];
    const float* w_proj = (const float*)d_in[3];
    const float* b_proj = (const float*)d_in[4];
    float* out = (float*)d_out;
    char* ws = (char*)d_ws;

    u16* xb      = (u16*)(ws + 0);          // 8192*768   bf16 = 12,582,912 B
    u16* wTa     = (u16*)(ws + 12582912);   // 2304*768   bf16 =  3,538,944 B
    u16* wTp     = (u16*)(ws + 16121856);   //  768*768   bf16 =  1,179,648 B
    u16* qkv     = (u16*)(ws + 17301504);   // 8192*2304  bf16 = 37,748,736 B
    u16* vt      = (u16*)(ws + 55050240);   // 48*64*2048 bf16 = 12,582,912 B
    u16* aout    = (u16*)(ws + 67633152);   // 8192*768   bf16 = 12,582,912 B
    // ts buffer reuses the xb region (xb's last consumer is gemm1, which runs earlier)
    float* ts_raw = (float*)(ws + 0);       // 48*32*64 f32 = 393,216 B (aliases xb)

    convx_kernel<<<dim3(2048), dim3(256), 0, stream>>>(x, xb, 8192 * 768 / 4);
    wtrans2_kernel<<<dim3(96, 24), dim3(32, 8), 0, stream>>>(w_attn, w_proj, wTa, wTp);
    gemm_kernel<true><<<dim3(18, 64), dim3(256), 0, stream>>>(xb, wTa, b_attn,
                                                              (void*)qkv, 8192, 2304, 768);
    vtrans_kernel<<<dim3(32, 48), dim3(256), 0, stream>>>(qkv, vt, ts_raw);
    attn_kernel<<<dim3(48, 32), dim3(256), 0, stream>>>(qkv, vt, ts_raw, aout);
    gemm_kernel<false><<<dim3(6, 64), dim3(256), 0, stream>>>(aout, wTp, b_proj,
                                                              (void*)out, 8192, 768, 768);
}

// Round 9
// 198.990 us; speedup vs baseline: 1.0599x; 1.0599x over previous
//
#include <hip/hip_runtime.h>
#include <cstdint>

typedef unsigned short u16;
typedef __bf16 bf16;
typedef bf16 bf16x8 __attribute__((ext_vector_type(8)));
typedef u16 u16x4 __attribute__((ext_vector_type(4)));
typedef u16 u16x8 __attribute__((ext_vector_type(8)));
typedef float f32x4 __attribute__((ext_vector_type(4)));

__device__ __forceinline__ u16 f2b(float f) {
    return __builtin_bit_cast(u16, (bf16)f);
}
__device__ __forceinline__ float b2f(u16 u) {
    return __uint_as_float(((unsigned)u) << 16);
}
__device__ __forceinline__ float ex2(float x) {
#if __has_builtin(__builtin_amdgcn_exp2f)
    return __builtin_amdgcn_exp2f(x);   // v_exp_f32: 2^x
#else
    return exp2f(x);
#endif
}
__device__ __forceinline__ void load_lds16(const void* g, void* l) {
    auto gp = reinterpret_cast<const __attribute__((address_space(1))) void*>(
        reinterpret_cast<uintptr_t>(g));
    auto lp = reinterpret_cast<__attribute__((address_space(3))) void*>(
        reinterpret_cast<uintptr_t>(l));
    __builtin_amdgcn_global_load_lds(gp, lp, 16, 0, 0);
}
__device__ __forceinline__ f32x4 mfma16(bf16x8 a, bf16x8 b, f32x4 c) {
    return __builtin_amdgcn_mfma_f32_16x16x32_bf16(a, b, c, 0, 0, 0);
}

#define LOG2E 1.44269504088896340736f

// ---------------------------------------------------------------- prep: x->bf16 + both weight transposes
__global__ __launch_bounds__(256) void prep_kernel(const float* __restrict__ x,
                                                   u16* __restrict__ xb,
                                                   const float* __restrict__ wa,
                                                   const float* __restrict__ wp,
                                                   u16* __restrict__ wTa,
                                                   u16* __restrict__ wTp) {
    __shared__ float tile[32][33];
    const int bx = blockIdx.x;
    if (bx < 2048) {
        const int n4 = 8192 * 768 / 4;
        int i = bx * 256 + threadIdx.x;
        for (; i < n4; i += 2048 * 256) {
            float4 v = ((const float4*)x)[i];
            u16x4 r;
            r[0] = f2b(v.x); r[1] = f2b(v.y); r[2] = f2b(v.z); r[3] = f2b(v.w);
            *(u16x4*)&xb[(size_t)i * 4] = r;
        }
        return;
    }
    const int idx = bx - 2048;          // [0, 2304): 96 n-tiles x 24 k-tiles
    const int nx = idx % 96, ky = idx / 96;
    const float* w;
    u16* wT;
    int N, n0;
    if (nx < 72) { w = wa; wT = wTa; N = 2304; n0 = nx * 32; }
    else         { w = wp; wT = wTp; N = 768;  n0 = (nx - 72) * 32; }
    const int K = 768, k0 = ky * 32;
    const int tx = threadIdx.x & 31, ty = threadIdx.x >> 5;
#pragma unroll
    for (int i = 0; i < 4; ++i)
        tile[ty + i * 8][tx] = w[(size_t)(k0 + ty + i * 8) * N + n0 + tx];
    __syncthreads();
#pragma unroll
    for (int i = 0; i < 4; ++i)
        wT[(size_t)(n0 + ty + i * 8) * K + k0 + tx] = f2b(tile[tx][ty + i * 8]);
}

// ---------------------------------------------------------------- GEMM: C[M][N] = A[M][K] * Bt[N][K]^T + bias
// MODE 0: plain f32 output (proj GEMM).
// MODE 1: qkv GEMM -- bf16 output; Q columns (col<768) pre-scaled by log2e;
//         V-region blocks (tn>=1536) write TRANSPOSED into vt[bh][d][s] and
//         reduce per-64-row column sums into ts_raw[bh][st][d] (no qkv write).
// 128x128 tile, 4 waves, 16x16x32 MFMA, dbuf gload_lds staging, swapped-operand
// epilogue (lane holds 4 consecutive C-columns), XCD-aware block swizzle.
template <int MODE>
__global__ __launch_bounds__(256, 2) void gemm_kernel(const u16* __restrict__ A,
                                                      const u16* __restrict__ Bt,
                                                      const float* __restrict__ bias,
                                                      void* __restrict__ out,
                                                      u16* __restrict__ vt,
                                                      float* __restrict__ ts_raw,
                                                      int M, int N, int K) {
    __shared__ __align__(16) u16 SMEM[4 * 128 * 64];   // A0,B0,A1,B1 (64 KB)
    const int tid = threadIdx.x;
    const int wave = tid >> 6, lane = tid & 63;
    const int l15 = lane & 15, lg = lane >> 4;
    const int gx = gridDim.x;
    const int nwg = gx * gridDim.y;
    const int lin = blockIdx.y * gx + blockIdx.x;
    const int swz = (lin & 7) * (nwg >> 3) + (lin >> 3);
    const int tm = (swz / gx) * 128, tn = (swz % gx) * 128;
    const int wr = (wave >> 1) * 64, wc = (wave & 1) * 64;

    f32x4 acc[4][4] = {};

    const int rbase = wave * 8 + (lane >> 3);
    const int sslot = (lane & 7) ^ (rbase & 7);
    const u16* gA = A + (size_t)(tm + rbase) * K + sslot * 8;
    const u16* gB = Bt + (size_t)(tn + rbase) * K + sslot * 8;
    const int woff = wave * 8 * 64;
    const int nkt = K >> 6;

#pragma unroll
    for (int i = 0; i < 4; ++i) {
        load_lds16(gA + (size_t)i * 32 * K, SMEM + woff + i * 32 * 64);
        load_lds16(gB + (size_t)i * 32 * K, SMEM + 8192 + woff + i * 32 * 64);
    }

    for (int kt = 0; kt < nkt; ++kt) {
        __syncthreads();  // buf[cur] ready (loads issued one iter ago); prev reads done
        const int cur = kt & 1;
        if (kt + 1 < nkt) {
            u16* ldsA = SMEM + (cur ^ 1) * 2 * 8192 + woff;
            u16* ldsB = ldsA + 8192;
#pragma unroll
            for (int i = 0; i < 4; ++i) {
                load_lds16(gA + (size_t)i * 32 * K + (kt + 1) * 64, ldsA + i * 32 * 64);
                load_lds16(gB + (size_t)i * 32 * K + (kt + 1) * 64, ldsB + i * 32 * 64);
            }
        }
        const u16* As = SMEM + cur * 2 * 8192;
        const u16* Bs = As + 8192;
#pragma unroll
        for (int kk = 0; kk < 64; kk += 32) {
            const int sb = kk >> 3;
            bf16x8 af[4], bfr[4];
#pragma unroll
            for (int m = 0; m < 4; ++m) {
                int row = wr + m * 16 + l15;
                af[m] = *(const bf16x8*)&As[row * 64 + (((sb + lg) ^ (row & 7))) * 8];
            }
#pragma unroll
            for (int n = 0; n < 4; ++n) {
                int row = wc + n * 16 + l15;
                bfr[n] = *(const bf16x8*)&Bs[row * 64 + (((sb + lg) ^ (row & 7))) * 8];
            }
#pragma unroll
            for (int m = 0; m < 4; ++m)
#pragma unroll
                for (int n = 0; n < 4; ++n)
                    acc[m][n] = mfma16(bfr[n], af[m], acc[m][n]);  // swapped: cols on regs
        }
    }

    if (MODE == 1 && tn >= 1536) {
        // V-region block: transposed store into vt + per-64-s-tile column sums.
        const int b = tm >> 11;
        const int s0 = (tm & 2047) + wr;          // wave's first s (64-aligned)
        const int st = s0 >> 6;
        const int hh = (tn + wc - 1536) >> 6;     // head index of this wave's 64 cols
        const int bh = b * 12 + hh;
        f32x4 colsum[4] = {};
#pragma unroll
        for (int m = 0; m < 4; ++m) {
            const int s = s0 + m * 16 + l15;
#pragma unroll
            for (int n = 0; n < 4; ++n) {
                const int col = tn + wc + n * 16 + lg * 4;
                f32x4 v = acc[m][n] + *(const f32x4*)&bias[col];
                colsum[n] += v;
                const int dl = n * 16 + lg * 4;
#pragma unroll
                for (int r = 0; r < 4; ++r)
                    vt[((size_t)bh * 64 + dl + r) * 2048 + s] = f2b(v[r]);
            }
        }
#pragma unroll
        for (int n = 0; n < 4; ++n)
#pragma unroll
            for (int off = 1; off < 16; off <<= 1) {
                colsum[n][0] += __shfl_xor(colsum[n][0], off);
                colsum[n][1] += __shfl_xor(colsum[n][1], off);
                colsum[n][2] += __shfl_xor(colsum[n][2], off);
                colsum[n][3] += __shfl_xor(colsum[n][3], off);
            }
        if (l15 == 0) {
#pragma unroll
            for (int n = 0; n < 4; ++n)
                *(f32x4*)&ts_raw[((size_t)bh * 32 + st) * 64 + n * 16 + lg * 4] =
                    colsum[n];
        }
        return;
    }

    const float sc = (MODE == 1 && tn < 768) ? LOG2E : 1.f;   // pre-scale Q by log2e
#pragma unroll
    for (int m = 0; m < 4; ++m) {
        const size_t row = (size_t)(tm + wr + m * 16 + l15);
#pragma unroll
        for (int n = 0; n < 4; ++n) {
            const int col = tn + wc + n * 16 + lg * 4;
            f32x4 v = (acc[m][n] + *(const f32x4*)&bias[col]) * sc;
            if constexpr (MODE == 1) {
                u16x4 pk;
#pragma unroll
                for (int r = 0; r < 4; ++r) pk[r] = f2b(v[r]);
                *(u16x4*)&((u16*)out)[row * N + col] = pk;
            } else {
                *(f32x4*)&((float*)out)[row * N + col] = v;
            }
        }
    }
}

// ---------------------------------------------------------------- attention
// Swapped-operand flash, QBLK=64, KBLK=64, defer-max in exp2 domain (Q pre-scaled
// by log2e in gemm1), K-row permutation so softmax'd P is ALREADY in PV's
// B-fragment layout (no P LDS round-trip). Unroll-by-2 main loop: static buffer
// indices -> loop-invariant LDS read addresses, constant-stride staging pointers.
// NOTE: staging dests are per-wave chunks (&Ks[b][ldsoff]); MFMA reads use the
// BUFFER BASE (Ks[b]) -- mixing these up was R7's NaN bug.
__global__ __launch_bounds__(256, 5) void attn_kernel(const u16* __restrict__ qkv,
                                                      const u16* __restrict__ vt,
                                                      const float* __restrict__ ts_raw,
                                                      u16* __restrict__ aout) {
    __shared__ __align__(16) u16 Ks[2][64 * 64];
    __shared__ __align__(16) u16 Vs[2][64 * 64];   // transposed V: [d][k]
    const int bh = blockIdx.x;                     // bh fastest: same-bh blocks share XCD L2
    const int qt = 31 - blockIdx.y;                // longest-first dispatch
    const int b = bh / 12, h = bh % 12;
    const int tid = threadIdx.x, wave = tid >> 6, lane = tid & 63;
    const int l15 = lane & 15, lg = lane >> 4;
    const int q0 = qt * 64 + wave * 16;
    const size_t rowbase = (size_t)b * 2048;
    const float MASKVAL = 1e-9f * LOG2E;           // reference's 1e-9, log2 domain
    const float THR2 = 8.0f * LOG2E;               // defer-max threshold (8 nats)

    bf16x8 qf[2];
#pragma unroll
    for (int ks = 0; ks < 2; ++ks)
        qf[ks] = *(const bf16x8*)(qkv + (rowbase + q0 + l15) * 2304 + h * 64 +
                                  ks * 32 + lg * 8);

    f32x4 o[4] = {};          // O^T: lane holds O[q=q0+l15][d = dn*16 + lg*4 + r]
    float mrun = -1e30f;      // running max, log2 domain
    f32x4 lacc = {};          // per-lane partial l, 4 ILP chains

    const int rbase = wave * 8 + (lane >> 3);
    const int sslot = (lane & 7) ^ (rbase & 7);
    const int sig0 = ((rbase & 0x1C) << 1) | (rbase & 3);   // K-row permutation base
    const u16* gK = qkv + (rowbase + sig0) * 2304 + 768 + h * 64 + sslot * 8;
    const u16* gV = vt + ((size_t)bh * 64 + rbase) * 2048 + sslot * 8;
    const int ldsoff = wave * 8 * 64;
    // staging destinations (per-wave chunk within each buffer)
    u16* sK0 = &Ks[0][ldsoff];
    u16* sK1 = &Ks[1][ldsoff];
    u16* sV0 = &Vs[0][ldsoff];
    u16* sV1 = &Vs[1][ldsoff];
    // loop-invariant swizzled slot offsets (row&7 == l15&7 for all fragment rows)
    const int xk0 = ((0 + lg) ^ (l15 & 7)) * 8;
    const int xk1 = ((4 + lg) ^ (l15 & 7)) * 8;

#define STAGE_PAIR(Kd, Vd, kp, vp)                       \
    load_lds16(kp, Kd);                                  \
    load_lds16(kp + (size_t)4 * 2304, Kd + 32 * 64);     \
    load_lds16(vp, Vd);                                  \
    load_lds16(vp + (size_t)32 * 2048, Vd + 32 * 64);

    auto process = [&](const u16* Kb, const u16* Vb, int kt) {   // Kb/Vb = BUFFER BASE
        f32x4 sacc[4] = {};
        __builtin_amdgcn_s_setprio(1);
#pragma unroll
        for (int n = 0; n < 4; ++n) {
            const int ra = (n * 16 + l15) * 64;
            sacc[n] = mfma16(*(const bf16x8*)&Kb[ra + xk0], qf[0], sacc[n]);
            sacc[n] = mfma16(*(const bf16x8*)&Kb[ra + xk1], qf[1], sacc[n]);
        }
        __builtin_amdgcn_s_setprio(0);

        if (kt == qt) {                       // diagonal tile mask (true k via sigma)
            const int q = q0 + l15;
            const int kb = kt * 64 + lg * 8;
#pragma unroll
            for (int n = 0; n < 4; ++n) {
                const int kn = kb + (n & 1) * 32 + ((n >> 1) << 2);
#pragma unroll
                for (int r = 0; r < 4; ++r)
                    if (kn + r > q) sacc[n][r] = MASKVAL;
            }
        }

        float mx = fmaxf(fmaxf(sacc[0][0], sacc[0][1]), fmaxf(sacc[0][2], sacc[0][3]));
#pragma unroll
        for (int n = 1; n < 4; ++n)
            mx = fmaxf(mx, fmaxf(fmaxf(sacc[n][0], sacc[n][1]),
                                 fmaxf(sacc[n][2], sacc[n][3])));
        if (__any(mx > mrun + THR2)) {
            float rm = fmaxf(mx, __shfl_xor(mx, 16));
            rm = fmaxf(rm, __shfl_xor(rm, 32));
            const float mnew = fmaxf(mrun, rm);
            const float alpha = ex2(mrun - mnew);
            mrun = mnew;
            lacc *= alpha;
#pragma unroll
            for (int dn = 0; dn < 4; ++dn) o[dn] *= alpha;
        }

#pragma unroll
        for (int n = 0; n < 4; ++n)
#pragma unroll
            for (int r = 0; r < 4; ++r)
                sacc[n][r] = ex2(sacc[n][r] - mrun);   // bounded by 2^11.5
        lacc += (sacc[0] + sacc[1]) + (sacc[2] + sacc[3]);

        bf16x8 bp0, bp1;
#pragma unroll
        for (int j = 0; j < 4; ++j) {
            bp0[j]     = (bf16)sacc[0][j];
            bp0[j + 4] = (bf16)sacc[2][j];
            bp1[j]     = (bf16)sacc[1][j];
            bp1[j + 4] = (bf16)sacc[3][j];
        }

        __builtin_amdgcn_s_setprio(1);
#pragma unroll
        for (int dn = 0; dn < 4; ++dn) {
            const int ra = (dn * 16 + l15) * 64;
            o[dn] = mfma16(*(const bf16x8*)&Vb[ra + xk0], bp0, o[dn]);
            o[dn] = mfma16(*(const bf16x8*)&Vb[ra + xk1], bp1, o[dn]);
        }
        __builtin_amdgcn_s_setprio(0);
    };

    const int nkt = qt + 1;
    STAGE_PAIR(sK0, sV0, gK, gV);             // prologue: tile 0 -> buf0
    const u16* gKp = gK + (size_t)64 * 2304;  // next tile to stage
    const u16* gVp = gV + 64;

    int kt = 0;
    for (;;) {
        __syncthreads();
        if (kt + 1 < nkt) {
            STAGE_PAIR(sK1, sV1, gKp, gVp);
            gKp += (size_t)64 * 2304; gVp += 64;
        }
        process(Ks[0], Vs[0], kt);
        if (++kt == nkt) break;
        __syncthreads();
        if (kt + 1 < nkt) {
            STAGE_PAIR(sK0, sV0, gKp, gVp);
            gKp += (size_t)64 * 2304; gVp += 64;
        }
        process(Ks[1], Vs[1], kt);
        if (++kt == nkt) break;
    }
#undef STAGE_PAIR

    float lrun = (lacc[0] + lacc[1]) + (lacc[2] + lacc[3]);
    lrun += __shfl_xor(lrun, 16);
    lrun += __shfl_xor(lrun, 32);

    // analytic future tail: all k >= (qt+1)*64 carry score exactly 1e-9
    if (qt < 31) {
        const float nf = (float)((31 - qt) * 64);
        const float mnew = fmaxf(mrun, MASKVAL);
        const float a = ex2(mrun - mnew);
        const float c = ex2(MASKVAL - mnew);
        lrun = lrun * a + nf * c;
        f32x4 suf[4] = {};
        for (int t = qt + 1; t < 32; ++t) {
            const float* sp = ts_raw + ((size_t)bh * 32 + t) * 64;
#pragma unroll
            for (int dn = 0; dn < 4; ++dn)
                suf[dn] += *(const f32x4*)&sp[dn * 16 + lg * 4];
        }
#pragma unroll
        for (int dn = 0; dn < 4; ++dn)
            o[dn] = o[dn] * a + suf[dn] * c;
    }

    const float inv = 1.f / lrun;
    const size_t row = rowbase + q0 + l15;
#pragma unroll
    for (int dn = 0; dn < 4; ++dn) {
        u16x4 st;
#pragma unroll
        for (int r = 0; r < 4; ++r) st[r] = f2b(o[dn][r] * inv);
        *(u16x4*)&aout[row * 768 + h * 64 + dn * 16 + lg * 4] = st;
    }
}

// ---------------------------------------------------------------- launch
extern "C" void kernel_launch(void* const* d_in, const int* in_sizes, int n_in,
                              void* d_out, int out_size, void* d_ws, size_t ws_size,
                              hipStream_t stream) {
    const float* x      = (const float*)d_in[0];
    const float* w_attn = (const float*)d_in[1];
    const float* b_attn = (const float*)d_in[2];
    const float* w_proj = (const float*)d_in[3];
    const float* b_proj = (const float*)d_in[4];
    float* out = (float*)d_out;
    char* ws = (char*)d_ws;

    u16* xb       = (u16*)(ws + 0);          // 8192*768   bf16 = 12,582,912 B
    u16* wTa      = (u16*)(ws + 12582912);   // 2304*768   bf16 =  3,538,944 B
    u16* wTp      = (u16*)(ws + 16121856);   //  768*768   bf16 =  1,179,648 B
    u16* qkv      = (u16*)(ws + 17301504);   // 8192*2304  bf16 = 37,748,736 B (V third unused)
    u16* vt       = (u16*)(ws + 55050240);   // 48*64*2048 bf16 = 12,582,912 B
    float* ts_raw = (float*)(ws + 67633152); // 48*32*64   f32  =    393,216 B
    u16* aout     = (u16*)(ws + 0);          // aliases xb (dead after gemm1)
    // high-water: 68,026,368 B

    prep_kernel<<<dim3(2048 + 2304), dim3(256), 0, stream>>>(x, xb, w_attn, w_proj,
                                                             wTa, wTp);
    gemm_kernel<1><<<dim3(18, 64), dim3(256), 0, stream>>>(xb, wTa, b_attn,
                                                           (void*)qkv, vt, ts_raw,
                                                           8192, 2304, 768);
    attn_kernel<<<dim3(48, 32), dim3(256), 0, stream>>>(qkv, vt, ts_raw, aout);
    gemm_kernel<0><<<dim3(6, 64), dim3(256), 0, stream>>>(aout, wTp, b_proj,
                                                          (void*)out, nullptr, nullptr,
                                                          8192, 768, 768);
}